// Round 3
// baseline (41945.468 us; speedup 1.0000x reference)
//
#include <hip/hip_runtime.h>
#include <cstdint>
#include <cstddef>

// LowRankRNN: h_{t+1} = h + coef*(-h + J@relu(h) + I_t),  J = G*W - B/N + M u v^T
// Persistent kernel: 64 blocks x 512 threads (8 waves), 1 block/CU on 64 CUs.
// Each wave owns 4 consecutive rows; J held in VGPRs (128 floats/lane).
// One device-wide barrier per timestep: single release fetch_add by tid0,
// ACQUIRE-load polling (L1-bypassing; relaxed polling read stale L1 -> R1 bug).

constexpr int   NN   = 2048;
constexpr int   TT   = 8192;
constexpr float COEF = 0.001f;             // DT/TAU
constexpr float G_   = 2.0f;
constexpr float BOFF = 10.0f / 2048.0f;    // B/N
constexpr float M_   = 1.5f;

constexpr int NBLK = 64;    // barrier participants (1 block/CU)
constexpr int TPB  = 512;   // 8 waves
constexpr int WPB  = TPB / 64;

typedef float f32x4 __attribute__((ext_vector_type(4)));  // native vec for nontemporal builtins

__global__ void init_ctr(unsigned int* ctr) {
  if (threadIdx.x == 0) *ctr = 0u;
}

__global__ __launch_bounds__(TPB, 2)
void rnn_persist(const float* __restrict__ I_t,
                 const float* __restrict__ h0,
                 const float* __restrict__ W,
                 const float* __restrict__ u,
                 const float* __restrict__ v,
                 float* __restrict__ out_h,   // d_out + TT, [TT][NN]
                 float* __restrict__ hbuf,    // 2*NN floats in d_ws (64B-aligned)
                 unsigned int* __restrict__ ctr)
{
  const int tid = threadIdx.x;
  const int l   = tid & 63;
  const int gw  = blockIdx.x * WPB + (tid >> 6);  // global wave 0..511
  const int rb  = gw * 4;                         // first of 4 consecutive rows
  const int cb  = l * 4;                          // column base within 256-chunk

  // ---- assemble J rows rb..rb+3 into registers: J[j][k] <-> row rb+j, cols k*256+4l
  float4 J[4][8];
#pragma unroll
  for (int j = 0; j < 4; ++j) {
    const float mu = M_ * u[rb + j];
#pragma unroll
    for (int k = 0; k < 8; ++k) {
      const int c = k * 256 + cb;
      const float4 w  = *(const float4*)(W + (size_t)(rb + j) * NN + c);
      const float4 vv = *(const float4*)(v + c);
      J[j][k].x = G_ * w.x - BOFF + mu * vv.x;
      J[j][k].y = G_ * w.y - BOFF + mu * vv.y;
      J[j][k].z = G_ * w.z - BOFF + mu * vv.z;
      J[j][k].w = G_ * w.w - BOFF + mu * vv.w;
    }
  }

  float h[4], icur[4];
#pragma unroll
  for (int j = 0; j < 4; ++j) {
    h[j]    = h0[rb + j];
    icur[j] = I_t[rb + j];   // row t=0
  }

  float* const buf0 = hbuf;
  float* const buf1 = hbuf + NN;

  for (int t = 0; t < TT; ++t) {
    // prefetch next I_t row early (independent of this step's compute)
    float inext[4] = {0.f, 0.f, 0.f, 0.f};
    if (t + 1 < TT) {
#pragma unroll
      for (int j = 0; j < 4; ++j)
        inext[j] = I_t[(size_t)(t + 1) * NN + rb + j];
    }

    const float* __restrict__ src = (t == 0) ? h0 : ((t & 1) ? buf1 : buf0);

    float p[4] = {0.f, 0.f, 0.f, 0.f};
#pragma unroll
    for (int k = 0; k < 8; ++k) {
      float4 xv = *(const float4*)(src + k * 256 + cb);
      xv.x = fmaxf(xv.x, 0.f);
      xv.y = fmaxf(xv.y, 0.f);
      xv.z = fmaxf(xv.z, 0.f);
      xv.w = fmaxf(xv.w, 0.f);
#pragma unroll
      for (int j = 0; j < 4; ++j) {
        p[j] = fmaf(J[j][k].x, xv.x, p[j]);
        p[j] = fmaf(J[j][k].y, xv.y, p[j]);
        p[j] = fmaf(J[j][k].z, xv.z, p[j]);
        p[j] = fmaf(J[j][k].w, xv.w, p[j]);
      }
    }

    // 64-lane butterflies: every lane ends with the full dot products
#pragma unroll
    for (int m = 32; m >= 1; m >>= 1) {
#pragma unroll
      for (int j = 0; j < 4; ++j) p[j] += __shfl_xor(p[j], m, 64);
    }

    // Euler update (all lanes redundantly; h feeds back via global buffer)
#pragma unroll
    for (int j = 0; j < 4; ++j) {
      h[j] = fmaf(COEF, p[j] + icur[j] - h[j], h[j]);
      icur[j] = inext[j];
    }

    float* const dst = (t & 1) ? buf0 : buf1;
    if (l == 0) {
      f32x4 hv;
      hv.x = h[0]; hv.y = h[1]; hv.z = h[2]; hv.w = h[3];
      *(f32x4*)(dst + rb) = hv;                                   // plain; flushed by release
      __builtin_nontemporal_store(hv, (f32x4*)(out_h + (size_t)t * NN + rb));
    }

    if (t + 1 < TT) {
      __syncthreads();   // implicit vmcnt(0): all waves' h stores are in L2
      if (tid == 0) {
        // release: waitcnt + buffer_wbl2 (flush this XCD's dirty h lines to LLC), then add
        __hip_atomic_fetch_add(ctr, 1u, __ATOMIC_RELEASE, __HIP_MEMORY_SCOPE_AGENT);
        const unsigned int target = (unsigned int)NBLK * (unsigned int)(t + 1);
        unsigned int spins = 0;
        // ACQUIRE polling: sc1 load bypasses stale L1/L2, buffer_inv on success
        while (__hip_atomic_load(ctr, __ATOMIC_ACQUIRE, __HIP_MEMORY_SCOPE_AGENT) < target) {
          __builtin_amdgcn_s_sleep(2);
          if (++spins > (1u << 24)) break;   // ~seconds; never hit when co-resident
        }
      }
      __syncthreads();
    }
  }
}

__global__ __launch_bounds__(256)
void readout(const float* __restrict__ h_all,
             const float* __restrict__ ro_w,
             const float* __restrict__ ro_b,
             float* __restrict__ y)
{
  __shared__ float red[4];
  const int t   = blockIdx.x;
  const int tid = threadIdx.x;
  const float* h = h_all + (size_t)t * NN;
  const int base = tid * 8;

  const float4 a0 = *(const float4*)(h + base);
  const float4 a1 = *(const float4*)(h + base + 4);
  const float4 w0 = *(const float4*)(ro_w + base);
  const float4 w1 = *(const float4*)(ro_w + base + 4);

  float s = a0.x * w0.x + a0.y * w0.y + a0.z * w0.z + a0.w * w0.w
          + a1.x * w1.x + a1.y * w1.y + a1.z * w1.z + a1.w * w1.w;
#pragma unroll
  for (int m = 32; m >= 1; m >>= 1) s += __shfl_xor(s, m, 64);

  if ((tid & 63) == 0) red[tid >> 6] = s;
  __syncthreads();
  if (tid == 0) y[t] = red[0] + red[1] + red[2] + red[3] + ro_b[0];
}

extern "C" void kernel_launch(void* const* d_in, const int* in_sizes, int n_in,
                              void* d_out, int out_size, void* d_ws, size_t ws_size,
                              hipStream_t stream)
{
  const float* I_t  = (const float*)d_in[0];
  const float* h0   = (const float*)d_in[1];
  const float* W    = (const float*)d_in[2];
  const float* u    = (const float*)d_in[3];
  const float* v    = (const float*)d_in[4];
  const float* ro_w = (const float*)d_in[5];
  const float* ro_b = (const float*)d_in[6];

  float* y    = (float*)d_out;             // [TT]
  float* outh = (float*)d_out + TT;        // [TT][NN]

  unsigned int* ctr = (unsigned int*)d_ws;
  float* hbuf = (float*)((char*)d_ws + 256);   // 2*NN floats, 64B-aligned

  init_ctr<<<1, 64, 0, stream>>>(ctr);
  rnn_persist<<<NBLK, TPB, 0, stream>>>(I_t, h0, W, u, v, outh, hbuf, ctr);
  readout<<<TT, 256, 0, stream>>>(outh, ro_w, ro_b, y);
}

// Round 4
// 32664.392 us; speedup vs baseline: 1.2841x; 1.2841x over previous
//
#include <hip/hip_runtime.h>
#include <cstdint>
#include <cstddef>

// LowRankRNN: h_{t+1} = h + coef*(-h + J@relu(h) + I_t),  J = G*W - B/N + M u v^T
// Persistent kernel: 64 blocks x 512 threads (1 block/CU). Each wave owns 4 rows;
// J held in VGPRs (128 floats/lane). Per-step device barrier via 64 per-block
// flags (one 128B line each): arrival = single RELEASE store; wave0 polls all
// 64 flags with one 64-lane RELAXED load/iter + ACQUIRE confirm (buffer_inv).
// out_h store + I_t prefetch hidden in the wait window.

constexpr int   NN   = 2048;
constexpr int   TT   = 8192;
constexpr float COEF = 0.001f;             // DT/TAU
constexpr float G_   = 2.0f;
constexpr float BOFF = 10.0f / 2048.0f;    // B/N
constexpr float M_   = 1.5f;

constexpr int NBLK = 64;    // barrier participants (1 block/CU)
constexpr int TPB  = 512;   // 8 waves
constexpr int WPB  = TPB / 64;

typedef float f32x4 __attribute__((ext_vector_type(4)));

__global__ void init_flags(unsigned int* flags) {
  // 64 threads: zero each block's flag word (ws is poisoned 0xAA by harness)
  flags[(size_t)threadIdx.x << 5] = 0u;
}

__global__ __launch_bounds__(TPB, 2)
void rnn_persist(const float* __restrict__ I_t,
                 const float* __restrict__ h0,
                 const float* __restrict__ W,
                 const float* __restrict__ u,
                 const float* __restrict__ v,
                 float* __restrict__ out_h,   // d_out + TT, [TT][NN]
                 float* __restrict__ hbuf,    // 2*NN floats
                 unsigned int* __restrict__ flags)  // 64 flags, 128B apart
{
  const int tid = threadIdx.x;
  const int l   = tid & 63;
  const int w   = tid >> 6;
  const int gw  = blockIdx.x * WPB + w;           // global wave 0..511
  const int rb  = gw * 4;                         // first of 4 consecutive rows
  const int cb  = l * 4;                          // column base within 256-chunk

  // ---- assemble J rows rb..rb+3: J[j][k] <-> row rb+j, cols k*256 + 4l
  float4 J[4][8];
#pragma unroll
  for (int j = 0; j < 4; ++j) {
    const float mu = M_ * u[rb + j];
#pragma unroll
    for (int k = 0; k < 8; ++k) {
      const int c = k * 256 + cb;
      const float4 wv = *(const float4*)(W + (size_t)(rb + j) * NN + c);
      const float4 vv = *(const float4*)(v + c);
      J[j][k].x = G_ * wv.x - BOFF + mu * vv.x;
      J[j][k].y = G_ * wv.y - BOFF + mu * vv.y;
      J[j][k].z = G_ * wv.z - BOFF + mu * vv.z;
      J[j][k].w = G_ * wv.w - BOFF + mu * vv.w;
    }
  }

  float h[4], icur[4];
#pragma unroll
  for (int j = 0; j < 4; ++j) {
    h[j]    = h0[rb + j];
    icur[j] = I_t[rb + j];   // row t=0
  }

  float* const buf0 = hbuf;
  float* const buf1 = hbuf + NN;

  for (int t = 0; t < TT; ++t) {
    const float* __restrict__ src = (t == 0) ? h0 : ((t & 1) ? buf1 : buf0);

    // ---- x read + dot products (critical path head)
    float p[4] = {0.f, 0.f, 0.f, 0.f};
#pragma unroll
    for (int k = 0; k < 8; ++k) {
      float4 xv = *(const float4*)(src + k * 256 + cb);
      xv.x = fmaxf(xv.x, 0.f);
      xv.y = fmaxf(xv.y, 0.f);
      xv.z = fmaxf(xv.z, 0.f);
      xv.w = fmaxf(xv.w, 0.f);
#pragma unroll
      for (int j = 0; j < 4; ++j) {
        p[j] = fmaf(J[j][k].x, xv.x, p[j]);
        p[j] = fmaf(J[j][k].y, xv.y, p[j]);
        p[j] = fmaf(J[j][k].z, xv.z, p[j]);
        p[j] = fmaf(J[j][k].w, xv.w, p[j]);
      }
    }
#pragma unroll
    for (int m = 32; m >= 1; m >>= 1) {
#pragma unroll
      for (int j = 0; j < 4; ++j) p[j] += __shfl_xor(p[j], m, 64);
    }
#pragma unroll
    for (int j = 0; j < 4; ++j)
      h[j] = fmaf(COEF, p[j] + icur[j] - h[j], h[j]);

    if (t + 1 < TT) {
      // new h to the swap buffer
      if (l == 0) {
        f32x4 hv; hv.x = h[0]; hv.y = h[1]; hv.z = h[2]; hv.w = h[3];
        *(f32x4*)(((t & 1) ? buf0 : buf1) + rb) = hv;
      }
      __syncthreads();   // every wave's h store vmcnt-drained into L2
      if (tid == 0) {
        // release: wbl2 (dirty h lines -> LLC) + flag store; no RMW contention
        __hip_atomic_store(&flags[(size_t)blockIdx.x << 5], (unsigned)(t + 1),
                           __ATOMIC_RELEASE, __HIP_MEMORY_SCOPE_AGENT);
      }
      // ---- wait-shadow work: out_h trace store + next I_t prefetch
      if (l == 0) {
        f32x4 hv; hv.x = h[0]; hv.y = h[1]; hv.z = h[2]; hv.w = h[3];
        __builtin_nontemporal_store(hv, (f32x4*)(out_h + (size_t)t * NN + rb));
      }
      float inext[4];
#pragma unroll
      for (int j = 0; j < 4; ++j)
        inext[j] = I_t[(size_t)(t + 1) * NN + rb + j];

      if (w == 0) {
        // lane i polls block i's flag: one 64-lane load per iteration
        const unsigned target = (unsigned)(t + 1);
        unsigned spins = 0;
        for (;;) {
          unsigned f = __hip_atomic_load(&flags[(size_t)l << 5],
                                         __ATOMIC_RELAXED, __HIP_MEMORY_SCOPE_AGENT);
          if (__all((int)(f >= target))) {
            // acquire confirm: buffer_inv so subsequent x reads see remote h
            f = __hip_atomic_load(&flags[(size_t)l << 5],
                                  __ATOMIC_ACQUIRE, __HIP_MEMORY_SCOPE_AGENT);
            if (__all((int)(f >= target))) break;
          }
          if (++spins > (1u << 22)) break;   // escape hatch; never hit when co-resident
        }
      }
      __syncthreads();
#pragma unroll
      for (int j = 0; j < 4; ++j) icur[j] = inext[j];
    } else {
      // final step: only the trace store matters
      if (l == 0) {
        f32x4 hv; hv.x = h[0]; hv.y = h[1]; hv.z = h[2]; hv.w = h[3];
        __builtin_nontemporal_store(hv, (f32x4*)(out_h + (size_t)t * NN + rb));
      }
    }
  }
}

__global__ __launch_bounds__(256)
void readout(const float* __restrict__ h_all,
             const float* __restrict__ ro_w,
             const float* __restrict__ ro_b,
             float* __restrict__ y)
{
  __shared__ float red[4];
  const int t   = blockIdx.x;
  const int tid = threadIdx.x;
  const float* h = h_all + (size_t)t * NN;
  const int base = tid * 8;

  const float4 a0 = *(const float4*)(h + base);
  const float4 a1 = *(const float4*)(h + base + 4);
  const float4 w0 = *(const float4*)(ro_w + base);
  const float4 w1 = *(const float4*)(ro_w + base + 4);

  float s = a0.x * w0.x + a0.y * w0.y + a0.z * w0.z + a0.w * w0.w
          + a1.x * w1.x + a1.y * w1.y + a1.z * w1.z + a1.w * w1.w;
#pragma unroll
  for (int m = 32; m >= 1; m >>= 1) s += __shfl_xor(s, m, 64);

  if ((tid & 63) == 0) red[tid >> 6] = s;
  __syncthreads();
  if (tid == 0) y[t] = red[0] + red[1] + red[2] + red[3] + ro_b[0];
}

extern "C" void kernel_launch(void* const* d_in, const int* in_sizes, int n_in,
                              void* d_out, int out_size, void* d_ws, size_t ws_size,
                              hipStream_t stream)
{
  const float* I_t  = (const float*)d_in[0];
  const float* h0   = (const float*)d_in[1];
  const float* W    = (const float*)d_in[2];
  const float* u    = (const float*)d_in[3];
  const float* v    = (const float*)d_in[4];
  const float* ro_w = (const float*)d_in[5];
  const float* ro_b = (const float*)d_in[6];

  float* y    = (float*)d_out;             // [TT]
  float* outh = (float*)d_out + TT;        // [TT][NN]

  unsigned int* flags = (unsigned int*)d_ws;               // 64 * 128 B = 8 KB
  float* hbuf = (float*)((char*)d_ws + 8192);              // 2*NN floats

  init_flags<<<1, 64, 0, stream>>>(flags);
  rnn_persist<<<NBLK, TPB, 0, stream>>>(I_t, h0, W, u, v, outh, hbuf, flags);
  readout<<<TT, 256, 0, stream>>>(outh, ro_w, ro_b, y);
}

// Round 5
// 29565.964 us; speedup vs baseline: 1.4187x; 1.1048x over previous
//
#include <hip/hip_runtime.h>
#include <cstdint>
#include <cstddef>

// LowRankRNN: h_{t+1} = h + coef*(-h + J@relu(h) + I_t),  J = G*W - B/N + M u v^T
// Persistent kernel: 64 blocks x 512 threads (1 block/CU). Each wave owns 4 rows;
// J held in VGPRs (128 floats/lane). Per-step device barrier: 64 per-block flag
// lines; arrival = RELEASE store by tid0 (after syncthreads vmcnt-drain);
// wave0 polls all 64 flags with one 64-lane ACQUIRE load/iter (buffer_inv free).
// h exchange is WRITE-THROUGH (agent relaxed atomic stores, L2-bypass) so h is
// at the LLC before the flag, not after the release-wbl2. Packed-FP32 FMA.

constexpr int   NN   = 2048;
constexpr int   TT   = 8192;
constexpr float COEF = 0.001f;             // DT/TAU
constexpr float G_   = 2.0f;
constexpr float BOFF = 10.0f / 2048.0f;    // B/N
constexpr float M_   = 1.5f;

constexpr int NBLK = 64;    // barrier participants (1 block/CU)
constexpr int TPB  = 512;   // 8 waves
constexpr int WPB  = TPB / 64;

typedef float f32x4 __attribute__((ext_vector_type(4)));

__global__ void init_flags(unsigned int* flags) {
  flags[(size_t)threadIdx.x << 5] = 0u;   // 64 flags, one per 128B line
}

__global__ __launch_bounds__(TPB, 2)
void rnn_persist(const float* __restrict__ I_t,
                 const float* __restrict__ h0,
                 const float* __restrict__ W,
                 const float* __restrict__ u,
                 const float* __restrict__ v,
                 float* __restrict__ out_h,   // d_out + TT, [TT][NN]
                 float* __restrict__ hbuf,    // 2*NN floats
                 unsigned int* __restrict__ flags)
{
  const int tid = threadIdx.x;
  const int l   = tid & 63;
  const int w   = tid >> 6;
  const int gw  = blockIdx.x * WPB + w;           // global wave 0..511
  const int rb  = gw * 4;                         // first of 4 consecutive rows
  const int cb  = l * 4;                          // column base within 256-chunk

  // ---- assemble J rows rb..rb+3: J[j][k] <-> row rb+j, cols k*256 + 4l
  f32x4 J[4][8];
#pragma unroll
  for (int j = 0; j < 4; ++j) {
    const float mu = M_ * u[rb + j];
#pragma unroll
    for (int k = 0; k < 8; ++k) {
      const int c = k * 256 + cb;
      const f32x4 wv = *(const f32x4*)(W + (size_t)(rb + j) * NN + c);
      const f32x4 vv = *(const f32x4*)(v + c);
      J[j][k] = G_ * wv - BOFF + mu * vv;
    }
  }

  float h[4], icur[4];
#pragma unroll
  for (int j = 0; j < 4; ++j) {
    h[j]    = h0[rb + j];
    icur[j] = I_t[rb + j];   // row t=0
  }

  float* const buf0 = hbuf;
  float* const buf1 = hbuf + NN;
  const f32x4 zero4 = {0.f, 0.f, 0.f, 0.f};

  for (int t = 0; t < TT; ++t) {
    const float* __restrict__ src = (t == 0) ? h0 : ((t & 1) ? buf1 : buf0);

    // ---- x read + packed dot products (critical path head)
    f32x4 p4[4] = {zero4, zero4, zero4, zero4};
#pragma unroll
    for (int k = 0; k < 8; ++k) {
      f32x4 xv = *(const f32x4*)(src + k * 256 + cb);
      xv = __builtin_elementwise_max(xv, zero4);   // relu -> v_pk_max_f32
#pragma unroll
      for (int j = 0; j < 4; ++j)
        p4[j] = __builtin_elementwise_fma(J[j][k], xv, p4[j]);  // v_pk_fma_f32
    }
    float p[4];
#pragma unroll
    for (int j = 0; j < 4; ++j)
      p[j] = (p4[j].x + p4[j].y) + (p4[j].z + p4[j].w);

#pragma unroll
    for (int m = 32; m >= 1; m >>= 1) {
#pragma unroll
      for (int j = 0; j < 4; ++j) p[j] += __shfl_xor(p[j], m, 64);
    }
#pragma unroll
    for (int j = 0; j < 4; ++j)
      h[j] = fmaf(COEF, p[j] + icur[j] - h[j], h[j]);

    if (t + 1 < TT) {
      // write-through h exchange: sc1 stores, en route to LLC before the flag
      if (l == 0) {
        float* const dst = (t & 1) ? buf0 : buf1;
        union { float f[2]; unsigned long long u; } a, b;
        a.f[0] = h[0]; a.f[1] = h[1]; b.f[0] = h[2]; b.f[1] = h[3];
        unsigned long long* dp = (unsigned long long*)(dst + rb);
        __hip_atomic_store(dp,     a.u, __ATOMIC_RELAXED, __HIP_MEMORY_SCOPE_AGENT);
        __hip_atomic_store(dp + 1, b.u, __ATOMIC_RELAXED, __HIP_MEMORY_SCOPE_AGENT);
      }
      __syncthreads();   // each wave vmcnt(0)-drains its h stores before barrier
      if (tid == 0) {
        // release: ordering fence + flag store (wbl2 cheap: L2 nearly clean)
        __hip_atomic_store(&flags[(size_t)blockIdx.x << 5], (unsigned)(t + 1),
                           __ATOMIC_RELEASE, __HIP_MEMORY_SCOPE_AGENT);
      }
      // ---- wait-shadow work: out_h trace store + next I_t prefetch
      if (l == 0) {
        f32x4 hv; hv.x = h[0]; hv.y = h[1]; hv.z = h[2]; hv.w = h[3];
        __builtin_nontemporal_store(hv, (f32x4*)(out_h + (size_t)t * NN + rb));
      }
      float inext[4];
#pragma unroll
      for (int j = 0; j < 4; ++j)
        inext[j] = I_t[(size_t)(t + 1) * NN + rb + j];

      if (w == 0) {
        // lane i polls block i's flag; ACQUIRE each iter (L1/L2-bypassing read,
        // buffer_inv on the iteration that succeeds) — no confirm trip
        const unsigned target = (unsigned)(t + 1);
        unsigned spins = 0;
        for (;;) {
          unsigned f = __hip_atomic_load(&flags[(size_t)l << 5],
                                         __ATOMIC_ACQUIRE, __HIP_MEMORY_SCOPE_AGENT);
          if (__all((int)(f >= target))) break;
          if (++spins > (1u << 22)) break;   // escape hatch; never hit co-resident
        }
      }
      __syncthreads();
#pragma unroll
      for (int j = 0; j < 4; ++j) icur[j] = inext[j];
    } else {
      if (l == 0) {
        f32x4 hv; hv.x = h[0]; hv.y = h[1]; hv.z = h[2]; hv.w = h[3];
        __builtin_nontemporal_store(hv, (f32x4*)(out_h + (size_t)t * NN + rb));
      }
    }
  }
}

__global__ __launch_bounds__(256)
void readout(const float* __restrict__ h_all,
             const float* __restrict__ ro_w,
             const float* __restrict__ ro_b,
             float* __restrict__ y)
{
  __shared__ float red[4];
  const int t   = blockIdx.x;
  const int tid = threadIdx.x;
  const float* h = h_all + (size_t)t * NN;
  const int base = tid * 8;

  const float4 a0 = *(const float4*)(h + base);
  const float4 a1 = *(const float4*)(h + base + 4);
  const float4 w0 = *(const float4*)(ro_w + base);
  const float4 w1 = *(const float4*)(ro_w + base + 4);

  float s = a0.x * w0.x + a0.y * w0.y + a0.z * w0.z + a0.w * w0.w
          + a1.x * w1.x + a1.y * w1.y + a1.z * w1.z + a1.w * w1.w;
#pragma unroll
  for (int m = 32; m >= 1; m >>= 1) s += __shfl_xor(s, m, 64);

  if ((tid & 63) == 0) red[tid >> 6] = s;
  __syncthreads();
  if (tid == 0) y[t] = red[0] + red[1] + red[2] + red[3] + ro_b[0];
}

extern "C" void kernel_launch(void* const* d_in, const int* in_sizes, int n_in,
                              void* d_out, int out_size, void* d_ws, size_t ws_size,
                              hipStream_t stream)
{
  const float* I_t  = (const float*)d_in[0];
  const float* h0   = (const float*)d_in[1];
  const float* W    = (const float*)d_in[2];
  const float* u    = (const float*)d_in[3];
  const float* v    = (const float*)d_in[4];
  const float* ro_w = (const float*)d_in[5];
  const float* ro_b = (const float*)d_in[6];

  float* y    = (float*)d_out;             // [TT]
  float* outh = (float*)d_out + TT;        // [TT][NN]

  unsigned int* flags = (unsigned int*)d_ws;               // 64 * 128 B
  float* hbuf = (float*)((char*)d_ws + 8192);              // 2*NN floats

  init_flags<<<1, 64, 0, stream>>>(flags);
  rnn_persist<<<NBLK, TPB, 0, stream>>>(I_t, h0, W, u, v, outh, hbuf, flags);
  readout<<<TT, 256, 0, stream>>>(outh, ro_w, ro_b, y);
}